// Round 6
// baseline (101.545 us; speedup 1.0000x reference)
//
#include <hip/hip_runtime.h>

// Barrier-free, LDS-free. 8 lanes per row, 8 rows per wave-iteration, 64 rows
// per wave total (one tile per wave; grid covers B exactly). Product dot in
// log2 space (v_log_f32 via __log2f), sum dot in f32. 3-step butterfly reduce
// within 8-lane groups leaves the sums in ALL 8 lanes; one ds_bpermute
// broadcast + conditional keep transposes results so lane L ends up owning
// row wbase+L. Then all 64 lanes run the transcendental chain in parallel and
// store coalesced. No __syncthreads -> no vmcnt(0) drains; waves independent.

__global__ __launch_bounds__(256) void funcblock_kernel(
    const float* __restrict__ x,
    const float* __restrict__ W_prod, const float* __restrict__ b_prod,
    const float* __restrict__ W_sum,  const float* __restrict__ b_sum,
    const float* __restrict__ w_dln,  const float* __restrict__ W_ln,
    const float* __restrict__ w_dsin, const float* __restrict__ W_sin,
    const float* __restrict__ w_dcos, const float* __restrict__ W_cos,
    const float* __restrict__ w_de,   const float* __restrict__ W_e,
    const float* __restrict__ w_dtanh,const float* __restrict__ W_tanh,
    float* __restrict__ out, int B)
{
    const int tid  = threadIdx.x;
    const int lane = tid & 63;
    const int wid  = tid >> 6;      // wave in block (0..3)
    const int u    = lane & 7;      // sub-lane within 8-lane row group
    const int g    = lane >> 3;     // row group (0..7)

    // Per-lane weight fragments: float4 indices u + 8j (matches x load pattern)
    float4 wp[4], ws[4];
    #pragma unroll
    for (int j = 0; j < 4; ++j) {
        wp[j] = reinterpret_cast<const float4*>(W_prod)[u + 8 * j];
        ws[j] = reinterpret_cast<const float4*>(W_sum)[u + 8 * j];
    }
    const float ws128 = W_sum[128];
    const float bp2 = b_prod[0] * 1.44269504088896340736f;  // exp -> exp2 fold
    const float bs = b_sum[0];
    const float wdln  = w_dln[0],  wln0  = W_ln[0],  wln1  = W_ln[1];
    const float wdsin = w_dsin[0], wsin0 = W_sin[0], wsin1 = W_sin[1];
    const float wdcos = w_dcos[0], wcos0 = W_cos[0], wcos1 = W_cos[1];
    const float wde   = w_de[0],   we0   = W_e[0],   we1   = W_e[1];
    const float wdtanh= w_dtanh[0],wt0   = W_tanh[0],wt1   = W_tanh[1];

    const int wbase = (blockIdx.x * 4 + wid) * 64;   // this wave's 64-row tile

    float pr = 0.0f, sr = 0.0f;     // this lane's owned-row results
    #pragma unroll 4
    for (int it = 0; it < 8; ++it) {
        const int row = wbase + it * 8 + g;
        float p = 0.0f, s = 0.0f;
        if (row < B) {
            const float4* xr =
                reinterpret_cast<const float4*>(x + (size_t)row * 128);
            float4 xv[4];
            #pragma unroll
            for (int j = 0; j < 4; ++j) xv[j] = xr[u + 8 * j];  // 4 indep loads
            #pragma unroll
            for (int j = 0; j < 4; ++j) {
                p += __log2f(__builtin_fabsf(xv[j].x)) * wp[j].x;
                p += __log2f(__builtin_fabsf(xv[j].y)) * wp[j].y;
                p += __log2f(__builtin_fabsf(xv[j].z)) * wp[j].z;
                p += __log2f(__builtin_fabsf(xv[j].w)) * wp[j].w;
                s += xv[j].x * ws[j].x + xv[j].y * ws[j].y
                   + xv[j].z * ws[j].z + xv[j].w * ws[j].w;
            }
        }
        #pragma unroll
        for (int m = 4; m >= 1; m >>= 1) {   // 3 steps, stays in 8-lane group
            p += __shfl_xor(p, m, 64);
            s += __shfl_xor(s, m, 64);
        }
        // Transpose-in-register: group (lane&7)'s sum -> lane; keep if my row.
        const float pb = __shfl(p, (lane & 7) * 8, 64);
        const float sb = __shfl(s, (lane & 7) * 8, 64);
        if (g == it) { pr = pb; sr = sb; }
    }

    // ---- Chain: 64 rows, one per lane, all lanes active ----
    const float x_prod = __builtin_amdgcn_exp2f(pr + bp2);   // v_exp_f32
    float h = sr + x_prod * ws128 + bs;
    float d;
    d = fmaxf(logf(fabsf(h)) * wdln, 0.0f);  h = d * wln0  + h * wln1;
    d = fmaxf(sinf(h) * wdsin, 0.0f);        h = d * wsin0 + h * wsin1;
    d = fmaxf(cosf(h) * wdcos, 0.0f);        h = d * wcos0 + h * wcos1;
    d = fmaxf(expf(h) * wde,   0.0f);        h = d * we0   + h * we1;
    d = fmaxf(tanhf(h) * wdtanh, 0.0f);      h = d * wt0   + h * wt1;
    const int orow = wbase + lane;
    if (orow < B) out[orow] = h;
}

extern "C" void kernel_launch(void* const* d_in, const int* in_sizes, int n_in,
                              void* d_out, int out_size, void* d_ws, size_t ws_size,
                              hipStream_t stream) {
    const float* x      = (const float*)d_in[0];
    const float* W_prod = (const float*)d_in[1];
    const float* b_prod = (const float*)d_in[2];
    const float* W_sum  = (const float*)d_in[3];
    const float* b_sum  = (const float*)d_in[4];
    const float* w_dln  = (const float*)d_in[5];
    const float* W_ln   = (const float*)d_in[6];
    const float* w_dsin = (const float*)d_in[7];
    const float* W_sin  = (const float*)d_in[8];
    const float* w_dcos = (const float*)d_in[9];
    const float* W_cos  = (const float*)d_in[10];
    const float* w_de   = (const float*)d_in[11];
    const float* W_e    = (const float*)d_in[12];
    const float* w_dtanh= (const float*)d_in[13];
    const float* W_tanh = (const float*)d_in[14];
    float* out = (float*)d_out;

    const int B = out_size;                 // 1048576 rows
    const int block = 256;                  // 4 waves, 64 rows each
    const int grid  = (B + 255) / 256;      // 4096: covers B exactly, no stride loop

    hipLaunchKernelGGL(funcblock_kernel, dim3(grid), dim3(block), 0, stream,
                       x, W_prod, b_prod, W_sum, b_sum,
                       w_dln, W_ln, w_dsin, W_sin, w_dcos, W_cos,
                       w_de, W_e, w_dtanh, W_tanh, out, B);
}